// Round 5
// baseline (412.241 us; speedup 1.0000x reference)
//
#include <hip/hip_runtime.h>

#define KCODES 4096
#define NROWS  32768
#define DIM    256           // K (plain bf16)
#define BM     64
#define BN     128
#define BK     64
#define NKT    (DIM / BK)    // 4 k-chunks
#define NJG    4             // j-groups (grid dim)
#define NJB    (KCODES / (BN * NJG))   // 8 j-tiles per block

typedef __attribute__((ext_vector_type(8))) short  short8;
typedef __attribute__((ext_vector_type(4))) float  float4v;

__device__ inline unsigned short f2bf(float f) {
    unsigned u = __float_as_uint(f);
    unsigned r = (u >> 16) & 1u;
    return (unsigned short)((u + 0x7FFFu + r) >> 16);   // RNE
}

// ---------------- kernel 0: codebook squared norms ----------------
__global__ __launch_bounds__(256) void csq_kernel(const float* __restrict__ cb,
                                                  float* __restrict__ csq) {
    int code = blockIdx.x * 256 + threadIdx.x;
    if (code < KCODES) {
        const float4* row = (const float4*)(cb + (size_t)code * DIM);
        float s = 0.f;
        #pragma unroll 8
        for (int i = 0; i < DIM / 4; ++i) {
            float4 v = row[i];
            s += v.x * v.x + v.y * v.y + v.z * v.z + v.w * v.w;
        }
        csq[code] = s;
    }
}

// ---------------- kernel 1: cb -> bf16 plane ----------------
__global__ __launch_bounds__(256) void conv_kernel(const float* __restrict__ cb,
                                                   unsigned short* __restrict__ B2) {
    const int idx = blockIdx.x * 256 + threadIdx.x;
    float4 v = ((const float4*)cb)[idx];
    ushort4 h = { f2bf(v.x), f2bf(v.y), f2bf(v.z), f2bf(v.w) };
    ((ushort4*)B2)[idx] = h;
}

// ---------------- kernel 2: K=256 bf16 GEMM, barrier-free main loop ----------------
// BM=64 (sA = 32 KB -> 4 blocks/CU), BN=128 split across 4 waves (distinct wn ->
// no intra-block B redundancy). B fragments loaded straight from the L2-resident
// codebook with register ping-pong prefetch; A reads are base+imm ds_reads;
// top-2 indices packed 16+16 into one u32 to fit the 128-VGPR budget.
// grid = 2048: jg = bid & 3, mB = bid >> 2
__global__ __launch_bounds__(256)
void gemm_top2_kernel(const float* __restrict__ x,
                      const unsigned short* __restrict__ B2,
                      const float* __restrict__ csq,
                      float4* __restrict__ pairs) {
    // A: 4 kt-regions x 512 slots x 8 bf16; slot(kt, r, kg) = kt*512 + r*8 + (kg ^ (r&7))
    __shared__ unsigned short sA[2048 * 8];   // 32 KB; aliased by merge scratch at the end

    const int tid = threadIdx.x;
    const int lane = tid & 63, wid = tid >> 6;
    const int wn = wid;                  // 4 waves = 4 column quarters of BN=128
    const int c = lane & 15, q = lane >> 4;
    const int jg = blockIdx.x & (NJG - 1);
    const int mB = blockIdx.x >> 2;
    const int mBase = mB * BM;

    // per-lane B row pointers (k-offset q*8 folded in); advanced by 128 rows per j-tile
    const unsigned short* pB0 = B2 + (size_t)(jg * (NJB * BN) + wn * 32 + c) * DIM + q * 8;
    const unsigned short* pB1 = pB0 + (size_t)16 * DIM;

    // issue the first B fragment pair immediately (hides under A staging)
    short8 bA0[2], bA1[2];
    bA0[0] = *(const short8*)pB0;
    bA0[1] = *(const short8*)pB1;

    // ---- stage A once: fp32 x -> bf16 LDS (XOR-swizzled) ----
    #pragma unroll
    for (int i = 0; i < 8; ++i) {
        int sid = i * 256 + tid;          // slot 0..2047
        int kt  = sid >> 9, rem = sid & 511;
        int r   = rem >> 3, kp  = rem & 7;
        int kgl = kp ^ (r & 7);
        const float4* xs = (const float4*)(x + (size_t)(mBase + r) * DIM + kt * BK + kgl * 8);
        float4 v0 = xs[0], v1 = xs[1];
        unsigned short h[8] = { f2bf(v0.x), f2bf(v0.y), f2bf(v0.z), f2bf(v0.w),
                                f2bf(v1.x), f2bf(v1.y), f2bf(v1.z), f2bf(v1.w) };
        *(short8*)&sA[(size_t)sid * 8] = *(short8*)h;
    }
    __syncthreads();   // A visible; the ONLY barrier before the merge

    // lane-constant LDS byte offsets for A fragment reads (ks = 0 / 1)
    const int cm = c & 7;
    const int laneA0 = c * 128 + ((q ^ cm) << 4);
    const int laneA1 = c * 128 + (((4 + q) ^ cm) << 4);
    const char* sAb = (const char*)sA;

    // running per-lane top-2 for the 16 (mi,e) row-slots; idx packed (i2<<16)|i1
    float rv1[16], rv2[16]; unsigned pk[16];
    #pragma unroll
    for (int s = 0; s < 16; ++s) { rv1[s] = INFINITY; rv2[s] = INFINITY; pk[s] = 0xFFFFFFFFu; }

#define TOP2(D, K, S) do {                                       \
        bool f1 = (D) < rv1[S];                                  \
        bool f2 = (D) < rv2[S];                                  \
        unsigned p = pk[S];                                      \
        pk[S]  = f1 ? ((p << 16) | (unsigned)(K))                \
                    : (f2 ? (((unsigned)(K) << 16) | (p & 0xFFFFu)) : p); \
        rv2[S] = f1 ? rv1[S] : (f2 ? (D) : rv2[S]);              \
        rv1[S] = f1 ? (D) : rv1[S];                              \
    } while (0)

    const float* pC = csq + jg * (NJB * BN) + wn * 32 + c;
    int k0 = jg * (NJB * BN) + wn * 32 + c;

    #pragma unroll 1
    for (int jj = 0; jj < NJB; ++jj) {
        float4v acc[4][2];
        #pragma unroll
        for (int mi = 0; mi < 4; ++mi)
            #pragma unroll
            for (int ni = 0; ni < 2; ++ni)
                #pragma unroll
                for (int e = 0; e < 4; ++e) acc[mi][ni][e] = 0.f;

        #pragma unroll
        for (int t = 0; t < 8; ++t) {
            const int kt  = t >> 1, ks = t & 1;
            const int ktn = ((t + 1) >> 1) & 3, ksn = (t + 1) & 1;

            if (t == 7) {   // advance to next j-tile before prefetching its first pair
                pB0 += (size_t)BN * DIM;
                pB1 += (size_t)BN * DIM;
            }
            // prefetch next subiter's B pair into the other buffer (WAR-bounded depth 1)
            short8* bNxt = (t & 1) ? bA0 : bA1;
            bNxt[0] = *(const short8*)((const char*)pB0 + ktn * 128 + ksn * 64);
            bNxt[1] = *(const short8*)((const char*)pB1 + ktn * 128 + ksn * 64);
            const short8* bCur = (t & 1) ? bA1 : bA0;

            const int laneA = ks ? laneA1 : laneA0;
            // first half: mi = 0,1
            {
                short8 a0 = *(const short8*)(sAb + laneA + kt * 8192 + 0 * 2048);
                short8 a1 = *(const short8*)(sAb + laneA + kt * 8192 + 1 * 2048);
                acc[0][0] = __builtin_amdgcn_mfma_f32_16x16x32_bf16(a0, bCur[0], acc[0][0], 0, 0, 0);
                acc[0][1] = __builtin_amdgcn_mfma_f32_16x16x32_bf16(a0, bCur[1], acc[0][1], 0, 0, 0);
                acc[1][0] = __builtin_amdgcn_mfma_f32_16x16x32_bf16(a1, bCur[0], acc[1][0], 0, 0, 0);
                acc[1][1] = __builtin_amdgcn_mfma_f32_16x16x32_bf16(a1, bCur[1], acc[1][1], 0, 0, 0);
            }
            // second half: mi = 2,3
            {
                short8 a2 = *(const short8*)(sAb + laneA + kt * 8192 + 2 * 2048);
                short8 a3 = *(const short8*)(sAb + laneA + kt * 8192 + 3 * 2048);
                acc[2][0] = __builtin_amdgcn_mfma_f32_16x16x32_bf16(a2, bCur[0], acc[2][0], 0, 0, 0);
                acc[2][1] = __builtin_amdgcn_mfma_f32_16x16x32_bf16(a2, bCur[1], acc[2][1], 0, 0, 0);
                acc[3][0] = __builtin_amdgcn_mfma_f32_16x16x32_bf16(a3, bCur[0], acc[3][0], 0, 0, 0);
                acc[3][1] = __builtin_amdgcn_mfma_f32_16x16x32_bf16(a3, bCur[1], acc[3][1], 0, 0, 0);
            }
        }

        // ---- per-j epilogue: dist = csq - 2*dot ; update running top-2 (ascending k) ----
        float cs0 = pC[0];
        float cs1 = pC[16];
        const int k1 = k0 + 16;

        #pragma unroll
        for (int mi = 0; mi < 4; ++mi)
            #pragma unroll
            for (int e = 0; e < 4; ++e) {
                const int sI = mi * 4 + e;
                float d0 = fmaf(-2.f, acc[mi][0][e], cs0);
                TOP2(d0, k0, sI);
                float d1 = fmaf(-2.f, acc[mi][1][e], cs1);
                TOP2(d1, k1, sI);
            }

        pC += BN;
        k0 += BN;
    }

    // ---- merge scratch aliased over sA (A no longer needed) ----
    __syncthreads();
    char* mbase = (char*)sA;
    float (*sV1)[BM] = (float(*)[BM])(mbase);
    int   (*sI1)[BM] = (int  (*)[BM])(mbase + 1024);
    float (*sV2)[BM] = (float(*)[BM])(mbase + 2048);
    int   (*sI2)[BM] = (int  (*)[BM])(mbase + 3072);

    // once per block: butterfly lex-merge of top-2 over the 16 c-lanes
    #pragma unroll
    for (int s = 0; s < 16; ++s) {
        float a1 = rv1[s], a2 = rv2[s];
        int   b1 = (int)(pk[s] & 0xFFFFu), b2 = (int)(pk[s] >> 16);
        #pragma unroll
        for (int m = 1; m < 16; m <<= 1) {
            float w1 = __shfl_xor(a1, m), w2 = __shfl_xor(a2, m);
            int   j1 = __shfl_xor(b1, m), j2 = __shfl_xor(b2, m);
            bool lt = (w1 < a1) || (w1 == a1 && j1 < b1);
            float f1v = lt ? w1 : a1;  int g1 = lt ? j1 : b1;
            float o1 = lt ? a1 : w1;   int p1 = lt ? b1 : j1;
            float o2 = lt ? w2 : a2;   int p2 = lt ? j2 : b2;
            bool lt2 = (o1 < o2) || (o1 == o2 && p1 < p2);
            a1 = f1v; b1 = g1;
            a2 = lt2 ? o1 : o2; b2 = lt2 ? p1 : p2;
        }
        if (c == 0) {
            int row = (s >> 2) * 16 + q * 4 + (s & 3);
            sV1[wn][row] = a1; sI1[wn][row] = b1;
            sV2[wn][row] = a2; sI2[wn][row] = b2;
        }
    }
    __syncthreads();

    // merge the four column-quarters, write (v1,i1,v2,i2) per row for this j-group
    if (tid < BM) {
        float a1 = sV1[0][tid], a2 = sV2[0][tid];
        int   b1 = sI1[0][tid], b2 = sI2[0][tid];
        #pragma unroll
        for (int g = 1; g < 4; ++g) {
            float w1 = sV1[g][tid], w2 = sV2[g][tid];
            int   j1 = sI1[g][tid], j2 = sI2[g][tid];
            bool lt = (w1 < a1) || (w1 == a1 && j1 < b1);
            float f1 = lt ? w1 : a1;  int g1 = lt ? j1 : b1;
            float o1 = lt ? a1 : w1;  int p1 = lt ? b1 : j1;
            float o2 = lt ? w2 : a2;  int p2 = lt ? j2 : b2;
            bool lt2 = (o1 < o2) || (o1 == o2 && p1 < p2);
            a1 = f1; b1 = g1;
            a2 = lt2 ? o1 : o2; b2 = lt2 ? p1 : p2;
        }
        float4 outp;
        outp.x = a1;  outp.y = __int_as_float(b1);
        outp.z = a2;  outp.w = __int_as_float(b2);
        pairs[(size_t)jg * NROWS + mBase + tid] = outp;   // [jg][row], coalesced
    }
#undef TOP2
}

// ---------------- kernel 3: merge 4 group-top-2 pairs -> top-4 indices ----------------
__global__ __launch_bounds__(256) void merge_kernel(const float4* __restrict__ pairs,
                                                    int* __restrict__ top4) {
    const int row = blockIdx.x * 256 + threadIdx.x;
    float tv[4] = { INFINITY, INFINITY, INFINITY, INFINITY };
    int   tk[4] = { 0x7FFFFFFF, 0x7FFFFFFF, 0x7FFFFFFF, 0x7FFFFFFF };
    for (int j = 0; j < NJG; ++j) {
        float4 p = pairs[(size_t)j * NROWS + row];
        #pragma unroll
        for (int h = 0; h < 2; ++h) {
            float v = h ? p.z : p.x;
            int   k = __float_as_int(h ? p.w : p.y);
            if (v < tv[3] || (v == tv[3] && k < tk[3])) {
                tv[3] = v; tk[3] = k;
                #pragma unroll
                for (int t = 3; t > 0; --t) {
                    bool lt = (tv[t] < tv[t-1]) || (tv[t] == tv[t-1] && tk[t] < tk[t-1]);
                    if (lt) {
                        float fv = tv[t]; tv[t] = tv[t-1]; tv[t-1] = fv;
                        int   fk = tk[t]; tk[t] = tk[t-1]; tk[t-1] = fk;
                    }
                }
            }
        }
    }
    #pragma unroll
    for (int t = 0; t < 4; ++t) top4[(size_t)row * 4 + t] = tk[t];
}

// ---------------- kernel 4: rescore with exact fp32 recipe + gather + loss ----------------
__global__ __launch_bounds__(256) void rescore_kernel(const float* __restrict__ x,
                                                      const float* __restrict__ cb,
                                                      const float* __restrict__ csq,
                                                      const int* __restrict__ top4,
                                                      float* __restrict__ out,
                                                      float* __restrict__ partial) {
    __shared__ float sx[64 * 256];   // 64 rows of x, raw fp32
    __shared__ float rv[64][4];
    __shared__ int   rk[64][4];
    __shared__ int   pick[64];
    __shared__ float sred[256];

    const int tid = threadIdx.x;
    const int rowBase = blockIdx.x * 64;
    const float4* x4 = (const float4*)x;
    const float4* c4 = (const float4*)cb;

    #pragma unroll
    for (int i = 0; i < 16; ++i) {
        int g = tid + i * 256;
        ((float4*)sx)[g] = x4[(size_t)rowBase * 64 + g];
    }
    __syncthreads();

    // one thread per (row, candidate): serial fmaf chain, ascending d
    {
        const int r = tid >> 2, ci = tid & 3;
        const int k = top4[(size_t)(rowBase + r) * 4 + ci];
        const float4* cr = c4 + (size_t)k * 64;
        const float4* xr = (const float4*)sx + r * 64;
        float acc = 0.f;
        for (int d4 = 0; d4 < 64; ++d4) {
            float4 cv = cr[d4];
            float4 xv = xr[d4];
            acc = fmaf(xv.x, cv.x, acc);
            acc = fmaf(xv.y, cv.y, acc);
            acc = fmaf(xv.z, cv.z, acc);
            acc = fmaf(xv.w, cv.w, acc);
        }
        float cs = csq[k];
        float v = cs - 2.0f * acc;
        rv[r][ci] = v;
        rk[r][ci] = k;
    }
    __syncthreads();

    if (tid < 64) {
        float bv = rv[tid][0];
        int   bi = rk[tid][0];
        #pragma unroll
        for (int t = 1; t < 4; ++t) {
            float v = rv[tid][t];
            int  ii = rk[tid][t];
            if (v < bv || (v == bv && ii < bi)) { bv = v; bi = ii; }
        }
        pick[tid] = bi;
    }
    __syncthreads();

    float s = 0.f;
    #pragma unroll
    for (int i = 0; i < 16; ++i) {
        int g = tid + i * 256;
        int r = g >> 6, col = g & 63;
        int k = pick[r];
        float4 cv = c4[(size_t)k * 64 + col];
        float4 xv = ((const float4*)sx)[g];
        ((float4*)out)[(size_t)rowBase * 64 + g] = cv;
        float dx = cv.x - xv.x, dy = cv.y - xv.y, dz = cv.z - xv.z, dw = cv.w - xv.w;
        s += dx * dx + dy * dy + dz * dz + dw * dw;
    }
    sred[tid] = s;
    __syncthreads();
    for (int off = 128; off > 0; off >>= 1) {
        if (tid < off) sred[tid] += sred[tid + off];
        __syncthreads();
    }
    if (tid == 0) partial[blockIdx.x] = sred[0];
}

// ---------------- kernel 5: finalize loss ----------------
__global__ __launch_bounds__(256) void finalize_kernel(const float* __restrict__ partial,
                                                       float* __restrict__ loss_out) {
    __shared__ float sred[256];
    const int tid = threadIdx.x;
    float s = 0.f;
    for (int i = tid; i < 512; i += 256) s += partial[i];
    sred[tid] = s;
    __syncthreads();
    for (int off = 128; off > 0; off >>= 1) {
        if (tid < off) sred[tid] += sred[tid + off];
        __syncthreads();
    }
    if (tid == 0) loss_out[0] = sred[0] * 1.25f / 8388608.0f;
}

extern "C" void kernel_launch(void* const* d_in, const int* in_sizes, int n_in,
                              void* d_out, int out_size, void* d_ws, size_t ws_size,
                              hipStream_t stream) {
    const float* x  = (const float*)d_in[0];
    const float* cb = (const float*)d_in[1];
    float* out = (float*)d_out;

    char* ws = (char*)d_ws;
    unsigned short* B2 = (unsigned short*)ws;                          // 2 MB
    float* csq         = (float*)(ws + 2097152);                       // 16 KB
    int*   top4        = (int*)(ws + 2097152 + 16384);                 // 512 KB
    float* partial     = (float*)(ws + 2097152 + 16384 + 524288);      // 2 KB

    // pairs scratch lives in d_out (2 MB used), fully overwritten by rescore afterwards
    float4* pairs = (float4*)d_out;

    conv_kernel<<<KCODES * 64 / 256, 256, 0, stream>>>(cb, B2);
    csq_kernel<<<KCODES / 256, 256, 0, stream>>>(cb, csq);
    gemm_top2_kernel<<<(NROWS / BM) * NJG, 256, 0, stream>>>(x, B2, csq, pairs);
    merge_kernel<<<NROWS / 256, 256, 0, stream>>>(pairs, top4);
    rescore_kernel<<<NROWS / 64, 256, 0, stream>>>(x, cb, csq, top4, out, partial);
    finalize_kernel<<<1, 256, 0, stream>>>(partial, out + 8388608);
}

// Round 6
// 251.647 us; speedup vs baseline: 1.6382x; 1.6382x over previous
//
#include <hip/hip_runtime.h>

#define KCODES 4096
#define NROWS  32768
#define DIM    256           // K (plain bf16)
#define BM     128
#define BN     64
#define BK     64
#define NKT    (DIM / BK)    // 4 k-chunks
#define NJG    4             // j-groups
#define NJB    (KCODES / (BN * NJG))   // 16 j-tiles per block

typedef __attribute__((ext_vector_type(8))) short  short8;
typedef __attribute__((ext_vector_type(4))) float  float4v;

__device__ inline unsigned short f2bf(float f) {
    unsigned u = __float_as_uint(f);
    unsigned r = (u >> 16) & 1u;
    return (unsigned short)((u + 0x7FFFu + r) >> 16);   // RNE
}
__device__ inline void load_lds16(const void* g, void* l) {
    __builtin_amdgcn_global_load_lds((const __attribute__((address_space(1))) void*)g,
                                     (__attribute__((address_space(3))) void*)l, 16, 0, 0);
}

// ---------------- kernel 0: codebook squared norms ----------------
__global__ __launch_bounds__(256) void csq_kernel(const float* __restrict__ cb,
                                                  float* __restrict__ csq) {
    int code = blockIdx.x * 256 + threadIdx.x;
    if (code < KCODES) {
        const float4* row = (const float4*)(cb + (size_t)code * DIM);
        float s = 0.f;
        #pragma unroll 8
        for (int i = 0; i < DIM / 4; ++i) {
            float4 v = row[i];
            s += v.x * v.x + v.y * v.y + v.z * v.z + v.w * v.w;
        }
        csq[code] = s;
    }
}

// ---------------- kernel 1: cb -> bf16 plane ----------------
__global__ __launch_bounds__(256) void conv_kernel(const float* __restrict__ cb,
                                                   unsigned short* __restrict__ B2) {
    const int idx = blockIdx.x * 256 + threadIdx.x;
    float4 v = ((const float4*)cb)[idx];
    ushort4 h = { f2bf(v.x), f2bf(v.y), f2bf(v.z), f2bf(v.w) };
    ((ushort4*)B2)[idx] = h;
}

// ---------------- kernel 1b: x -> bf16, PRE-SWIZZLED into gemm's sA slot layout ----------
// slot(sid) within an mB-tile: kt=sid>>10, r=(sid&1023)>>3, kp=sid&7, kgl=kp^(r&7)
// A2[mB*4096 + sid][0..7] = f2bf(x[mB*128 + r][kt*64 + kgl*8 .. +8])
// gemm then stages A with linear global_load_lds (DMA, zero VALU, swizzle pre-applied).
__global__ __launch_bounds__(256) void conv_x_kernel(const float* __restrict__ x,
                                                     unsigned short* __restrict__ A2) {
    const int g   = blockIdx.x * 256 + threadIdx.x;   // 0 .. 1048575 (one slot each)
    const int mB  = g >> 12;
    const int sid = g & 4095;
    const int kt  = sid >> 10, rem = sid & 1023;
    const int r   = rem >> 3,  kp  = rem & 7;
    const int kgl = kp ^ (r & 7);
    const float4* xs = (const float4*)(x + (size_t)(mB * BM + r) * DIM + kt * BK + kgl * 8);
    float4 v0 = xs[0], v1 = xs[1];
    unsigned short h[8] = { f2bf(v0.x), f2bf(v0.y), f2bf(v0.z), f2bf(v0.w),
                            f2bf(v1.x), f2bf(v1.y), f2bf(v1.z), f2bf(v1.w) };
    ((short8*)A2)[g] = *(short8*)h;
}

// ---------------- kernel 2: K=256 bf16 GEMM (R1 schedule, DMA A-stage, XCD swizzle) ----
// A resident in LDS (64 KB, staged once via global_load_lds from pre-swizzled A2).
// B double-buffered 2x8KB, counted vmcnt, raw barriers. grid = 1024.
// XCD swizzle: jg=(h>>3)&3, mB=(h&7)|((h>>5)<<3) -> 4 jg-blocks of one mB share an XCD L2.
__global__ __launch_bounds__(256, 2) void gemm_top2_kernel(const unsigned short* __restrict__ A2,
                                                           const unsigned short* __restrict__ B2,
                                                           const float* __restrict__ csq,
                                                           float4* __restrict__ pairs) {
    // A: 4 kt-regions x 1024 slots x 8 bf16; slot(kt, r, kg) = kt*1024 + r*8 + (kg ^ (r&7))
    __shared__ unsigned short sA[4096 * 8];   // 64 KB
    __shared__ unsigned short sB[2][4096];    // 16 KB (aliased by merge arrays at the end)

    const int tid = threadIdx.x;
    const int lane = tid & 63, wid = tid >> 6;
    const int wm = wid >> 1, wn = wid & 1;
    const int c = lane & 15, q = lane >> 4;
    const int h  = blockIdx.x;
    const int jg = (h >> 3) & 3;
    const int mB = (h & 7) | ((h >> 5) << 3);

    // ---- stage A: pure DMA from pre-swizzled A2 (16 x 16B per thread, linear) ----
    {
        const unsigned short* Ag = A2 + (size_t)mB * 4096 * 8;
        #pragma unroll
        for (int i = 0; i < 16; ++i) {
            int sid = i * 256 + tid;
            load_lds16(Ag + (size_t)sid * 8, &sA[(size_t)sid * 8]);
        }
    }

    // B staging descriptors (XOR-swizzled)
    unsigned gBrel[2];
    int ldsOff[2];
    #pragma unroll
    for (int i = 0; i < 2; ++i) {
        int s  = wid * 128 + i * 64 + lane;   // slot 0..511
        int r  = s >> 3, kgp = s & 7;
        int kg = kgp ^ (r & 7);
        gBrel[i]  = (unsigned)r * DIM + kg * 8;
        ldsOff[i] = (wid * 128 + i * 64) * 8;  // wave-uniform ushort offset
    }

#define STAGE(JJ, KT, PAR) do {                                                        \
        const unsigned short* gb = B2 + (size_t)((jg * NJB + (JJ)) * BN) * DIM + (KT) * BK; \
        load_lds16(gb + gBrel[0], &sB[PAR][ldsOff[0]]);                                \
        load_lds16(gb + gBrel[1], &sB[PAR][ldsOff[1]]);                                \
    } while (0)

#define TOP2(D, K, S) do {                                   \
        bool f1 = (D) < rv1[S];                              \
        bool f2 = (D) < rv2[S];                              \
        rv2[S] = f1 ? rv1[S] : (f2 ? (D) : rv2[S]);          \
        ri2[S] = f1 ? ri1[S] : (f2 ? (K) : ri2[S]);          \
        rv1[S] = f1 ? (D) : rv1[S];                          \
        ri1[S] = f1 ? (K) : ri1[S];                          \
    } while (0)

    // running per-lane top-2 for the 16 (mi,r) row-slots, carried across all 16 j-tiles
    float rv1[16], rv2[16]; int ri1[16], ri2[16];
    #pragma unroll
    for (int s = 0; s < 16; ++s) { rv1[s] = INFINITY; rv2[s] = INFINITY; ri1[s] = 0x7FFFFFFF; ri2[s] = 0x7FFFFFFF; }

    // ---- pipeline prologue: A DMA in flight, prefetch first two B chunks ----
    STAGE(0, 0, 0);
    STAGE(0, 1, 1);
    asm volatile("s_waitcnt vmcnt(4)" ::: "memory");     // A's 16 loads done; 4 B loads flying
    __builtin_amdgcn_s_barrier();                        // A visible; B(0),B(1) in flight

    #pragma unroll 1
    for (int jj = 0; jj < NJB; ++jj) {
        const int jBase = (jg * NJB + jj) * BN;
        float4v acc[4][2];
        #pragma unroll
        for (int mi = 0; mi < 4; ++mi)
            #pragma unroll
            for (int ni = 0; ni < 2; ++ni)
                #pragma unroll
                for (int e = 0; e < 4; ++e) acc[mi][ni][e] = 0.f;

        #pragma unroll
        for (int kt = 0; kt < NKT; ++kt) {
            // counted wait: current chunk landed, next chunk may stay in flight
            if (kt == 3 && jj == NJB - 1)
                asm volatile("s_waitcnt vmcnt(0)" ::: "memory");
            else
                asm volatile("s_waitcnt vmcnt(2)" ::: "memory");
            __builtin_amdgcn_s_barrier();
            asm volatile("" ::: "memory");

            const unsigned short* sBb = sB[kt & 1];
            #pragma unroll
            for (int ks = 0; ks < 2; ++ks) {
                short8 aF[4], bF[2];
                const int kg = ks * 4 + q;
                #pragma unroll
                for (int mi = 0; mi < 4; ++mi) {
                    int r = wm * 64 + mi * 16 + c;
                    aF[mi] = *(const short8*)&sA[(size_t)(kt * 1024 + r * 8 + (kg ^ (r & 7))) * 8];
                }
                #pragma unroll
                for (int ni = 0; ni < 2; ++ni) {
                    int r = wn * 32 + ni * 16 + c;
                    bF[ni] = *(const short8*)&sBb[(size_t)(r * 8 + (kg ^ (r & 7))) * 8];
                }
                #pragma unroll
                for (int mi = 0; mi < 4; ++mi)
                    #pragma unroll
                    for (int ni = 0; ni < 2; ++ni)
                        acc[mi][ni] = __builtin_amdgcn_mfma_f32_16x16x32_bf16(aF[mi], bF[ni], acc[mi][ni], 0, 0, 0);
            }

            asm volatile("" ::: "memory");
            __builtin_amdgcn_s_barrier();       // all waves done reading sB[kt&1]
            asm volatile("" ::: "memory");

            if (kt == 0)      STAGE(jj, 2, 0);
            else if (kt == 1) STAGE(jj, 3, 1);
            else if (kt == 2) { if (jj + 1 < NJB) STAGE(jj + 1, 0, 0); }
            // kt == 3: next-tile stage issued below, after the csq loads
        }

        // ---- per-j epilogue: dist = csq - 2*dot ; update running top-2 (ascending k) ----
        float cs0 = csq[jBase + wn * 32 + c];          // issued BEFORE the last stage so the
        float cs1 = csq[jBase + wn * 32 + 16 + c];     // compiler's wait is vmcnt(2), not 0
        asm volatile("" ::: "memory");
        if (jj + 1 < NJB) STAGE(jj + 1, 1, 1);         // overlaps with epilogue VALU below

        #pragma unroll
        for (int mi = 0; mi < 4; ++mi)
            #pragma unroll
            for (int r = 0; r < 4; ++r) {
                const int sI = mi * 4 + r;
                float d0 = fmaf(-2.f, acc[mi][0][r], cs0);
                int   k0 = jBase + wn * 32 + c;
                TOP2(d0, k0, sI);
                float d1 = fmaf(-2.f, acc[mi][1][r], cs1);
                int   k1 = jBase + wn * 32 + 16 + c;
                TOP2(d1, k1, sI);
            }
    }

    // ---- merge scratch aliased over sB (no longer needed) ----
    __syncthreads();
    char* mbase = (char*)sB;
    float (*sV1)[BM] = (float(*)[BM])(mbase);
    int   (*sI1)[BM] = (int  (*)[BM])(mbase + 1024);
    float (*sV2)[BM] = (float(*)[BM])(mbase + 2048);
    int   (*sI2)[BM] = (int  (*)[BM])(mbase + 3072);

    // once per block: butterfly lex-merge of top-2 over the 16 c-lanes
    #pragma unroll
    for (int s = 0; s < 16; ++s) {
        float a1 = rv1[s], a2 = rv2[s]; int b1 = ri1[s], b2 = ri2[s];
        #pragma unroll
        for (int m = 1; m < 16; m <<= 1) {
            float w1 = __shfl_xor(a1, m), w2 = __shfl_xor(a2, m);
            int   j1 = __shfl_xor(b1, m), j2 = __shfl_xor(b2, m);
            bool lt = (w1 < a1) || (w1 == a1 && j1 < b1);
            float f1v = lt ? w1 : a1;  int g1 = lt ? j1 : b1;
            float o1 = lt ? a1 : w1;   int p1 = lt ? b1 : j1;
            float o2 = lt ? w2 : a2;   int p2 = lt ? j2 : b2;
            bool lt2 = (o1 < o2) || (o1 == o2 && p1 < p2);
            a1 = f1v; b1 = g1;
            a2 = lt2 ? o1 : o2; b2 = lt2 ? p1 : p2;
        }
        if (c == 0) {
            int row = wm * 64 + (s >> 2) * 16 + q * 4 + (s & 3);
            sV1[wn][row] = a1; sI1[wn][row] = b1;
            sV2[wn][row] = a2; sI2[wn][row] = b2;
        }
    }
    __syncthreads();

    // merge the two code-halves, write (v1,i1,v2,i2) per row for this j-group
    if (tid < BM) {
        float a1 = sV1[0][tid], a2 = sV2[0][tid];
        int   b1 = sI1[0][tid], b2 = sI2[0][tid];
        float w1 = sV1[1][tid], w2 = sV2[1][tid];
        int   j1 = sI1[1][tid], j2 = sI2[1][tid];
        bool lt = (w1 < a1) || (w1 == a1 && j1 < b1);
        float f1 = lt ? w1 : a1;  int g1 = lt ? j1 : b1;
        float o1 = lt ? a1 : w1;  int p1 = lt ? b1 : j1;
        float o2 = lt ? w2 : a2;  int p2 = lt ? j2 : b2;
        bool lt2 = (o1 < o2) || (o1 == o2 && p1 < p2);
        float s2v = lt2 ? o1 : o2; int s2i = lt2 ? p1 : p2;
        float4 outp;
        outp.x = f1;  outp.y = __int_as_float(g1);
        outp.z = s2v; outp.w = __int_as_float(s2i);
        pairs[(size_t)jg * NROWS + mB * BM + tid] = outp;   // [jg][row], coalesced
    }
#undef STAGE
#undef TOP2
}

// ---------------- kernel 3: merge 4 group-top-2 pairs -> top-4 indices ----------------
__global__ __launch_bounds__(256) void merge_kernel(const float4* __restrict__ pairs,
                                                    int* __restrict__ top4) {
    const int row = blockIdx.x * 256 + threadIdx.x;
    float tv[4] = { INFINITY, INFINITY, INFINITY, INFINITY };
    int   tk[4] = { 0x7FFFFFFF, 0x7FFFFFFF, 0x7FFFFFFF, 0x7FFFFFFF };
    for (int j = 0; j < NJG; ++j) {
        float4 p = pairs[(size_t)j * NROWS + row];
        #pragma unroll
        for (int h = 0; h < 2; ++h) {
            float v = h ? p.z : p.x;
            int   k = __float_as_int(h ? p.w : p.y);
            if (v < tv[3] || (v == tv[3] && k < tk[3])) {
                tv[3] = v; tk[3] = k;
                #pragma unroll
                for (int t = 3; t > 0; --t) {
                    bool lt = (tv[t] < tv[t-1]) || (tv[t] == tv[t-1] && tk[t] < tk[t-1]);
                    if (lt) {
                        float fv = tv[t]; tv[t] = tv[t-1]; tv[t-1] = fv;
                        int   fk = tk[t]; tk[t] = tk[t-1]; tk[t-1] = fk;
                    }
                }
            }
        }
    }
    #pragma unroll
    for (int t = 0; t < 4; ++t) top4[(size_t)row * 4 + t] = tk[t];
}

// ---------------- kernel 4: rescore with exact fp32 recipe + gather + loss ----------------
__global__ __launch_bounds__(256) void rescore_kernel(const float* __restrict__ x,
                                                      const float* __restrict__ cb,
                                                      const float* __restrict__ csq,
                                                      const int* __restrict__ top4,
                                                      float* __restrict__ out,
                                                      float* __restrict__ partial) {
    __shared__ float sx[64 * 256];   // 64 rows of x, raw fp32
    __shared__ float rv[64][4];
    __shared__ int   rk[64][4];
    __shared__ int   pick[64];
    __shared__ float sred[256];

    const int tid = threadIdx.x;
    const int rowBase = blockIdx.x * 64;
    const float4* x4 = (const float4*)x;
    const float4* c4 = (const float4*)cb;

    #pragma unroll
    for (int i = 0; i < 16; ++i) {
        int g = tid + i * 256;
        ((float4*)sx)[g] = x4[(size_t)rowBase * 64 + g];
    }
    __syncthreads();

    // one thread per (row, candidate): serial fmaf chain, ascending d
    {
        const int r = tid >> 2, ci = tid & 3;
        const int k = top4[(size_t)(rowBase + r) * 4 + ci];
        const float4* cr = c4 + (size_t)k * 64;
        const float4* xr = (const float4*)sx + r * 64;
        float acc = 0.f;
        for (int d4 = 0; d4 < 64; ++d4) {
            float4 cv = cr[d4];
            float4 xv = xr[d4];
            acc = fmaf(xv.x, cv.x, acc);
            acc = fmaf(xv.y, cv.y, acc);
            acc = fmaf(xv.z, cv.z, acc);
            acc = fmaf(xv.w, cv.w, acc);
        }
        float cs = csq[k];
        float v = cs - 2.0f * acc;
        rv[r][ci] = v;
        rk[r][ci] = k;
    }
    __syncthreads();

    if (tid < 64) {
        float bv = rv[tid][0];
        int   bi = rk[tid][0];
        #pragma unroll
        for (int t = 1; t < 4; ++t) {
            float v = rv[tid][t];
            int  ii = rk[tid][t];
            if (v < bv || (v == bv && ii < bi)) { bv = v; bi = ii; }
        }
        pick[tid] = bi;
    }
    __syncthreads();

    float s = 0.f;
    #pragma unroll
    for (int i = 0; i < 16; ++i) {
        int g = tid + i * 256;
        int r = g >> 6, col = g & 63;
        int k = pick[r];
        float4 cv = c4[(size_t)k * 64 + col];
        float4 xv = ((const float4*)sx)[g];
        ((float4*)out)[(size_t)rowBase * 64 + g] = cv;
        float dx = cv.x - xv.x, dy = cv.y - xv.y, dz = cv.z - xv.z, dw = cv.w - xv.w;
        s += dx * dx + dy * dy + dz * dz + dw * dw;
    }
    sred[tid] = s;
    __syncthreads();
    for (int off = 128; off > 0; off >>= 1) {
        if (tid < off) sred[tid] += sred[tid + off];
        __syncthreads();
    }
    if (tid == 0) partial[blockIdx.x] = sred[0];
}

// ---------------- kernel 5: finalize loss ----------------
__global__ __launch_bounds__(256) void finalize_kernel(const float* __restrict__ partial,
                                                       float* __restrict__ loss_out) {
    __shared__ float sred[256];
    const int tid = threadIdx.x;
    float s = 0.f;
    for (int i = tid; i < 512; i += 256) s += partial[i];
    sred[tid] = s;
    __syncthreads();
    for (int off = 128; off > 0; off >>= 1) {
        if (tid < off) sred[tid] += sred[tid + off];
        __syncthreads();
    }
    if (tid == 0) loss_out[0] = sred[0] * 1.25f / 8388608.0f;
}

extern "C" void kernel_launch(void* const* d_in, const int* in_sizes, int n_in,
                              void* d_out, int out_size, void* d_ws, size_t ws_size,
                              hipStream_t stream) {
    const float* x  = (const float*)d_in[0];
    const float* cb = (const float*)d_in[1];
    float* out = (float*)d_out;

    char* ws = (char*)d_ws;
    unsigned short* B2 = (unsigned short*)ws;                          // 2 MB
    float* csq         = (float*)(ws + 2097152);                       // 16 KB
    int*   top4        = (int*)(ws + 2097152 + 16384);                 // 512 KB
    float* partial     = (float*)(ws + 2097152 + 16384 + 524288);      // 2 KB

    // scratch carved out of d_out (32 MB):
    //   pairs: [0, 2 MB)      — consumed by merge, then overwritten by rescore
    //   A2:    [2 MB, 18 MB)  — pre-swizzled bf16 x; dead before rescore overwrites
    float4*         pairs = (float4*)d_out;
    unsigned short* A2    = (unsigned short*)((char*)d_out + 2097152);

    conv_kernel<<<KCODES * 64 / 256, 256, 0, stream>>>(cb, B2);
    csq_kernel<<<KCODES / 256, 256, 0, stream>>>(cb, csq);
    conv_x_kernel<<<NROWS * DIM / 8 / 256, 256, 0, stream>>>(x, A2);
    gemm_top2_kernel<<<(NROWS / BM) * NJG, 256, 0, stream>>>(A2, B2, csq, pairs);
    merge_kernel<<<NROWS / 256, 256, 0, stream>>>(pairs, top4);
    rescore_kernel<<<NROWS / 64, 256, 0, stream>>>(x, cb, csq, top4, out, partial);
    finalize_kernel<<<1, 256, 0, stream>>>(partial, out + 8388608);
}